// Round 1
// baseline (36.931 us; speedup 1.0000x reference)
//
#include <hip/hip_runtime.h>
#include <cstddef>
#include <cstdint>

// RoIPool: features (B=2, C=256, H=50, W=50) f32, rois (R,4) f32, roi_indices (R,) int
// out (R, C, 7, 7) f32.
// Reference quirk preserved: h-bins from x coords (ri[:,0], ri[:,2]), w-bins from y.

namespace {
constexpr int OUTP = 7;
constexpr int BB = 2;
constexpr int CC = 256;
constexpr int HH = 50;
constexpr int WW = 50;
constexpr int HWSZ = HH * WW;
constexpr float NEGV = -3e38f;
}  // namespace

// (B, C, H*W) -> (B, H*W, C) tiled transpose via LDS.
__global__ __launch_bounds__(256) void transpose_k(const float* __restrict__ in,
                                                   float* __restrict__ out) {
    __shared__ float tile[32][33];
    const int b = blockIdx.z;
    const int hw0 = blockIdx.x * 32;
    const int c0 = blockIdx.y * 32;
    const int tx = threadIdx.x;
#pragma unroll
    for (int i = threadIdx.y; i < 32; i += 8) {
        const int hw = hw0 + tx;
        float v = 0.0f;
        if (hw < HWSZ) v = in[(size_t)(b * CC + c0 + i) * HWSZ + hw];
        tile[i][tx] = v;
    }
    __syncthreads();
#pragma unroll
    for (int i = threadIdx.y; i < 32; i += 8) {
        const int hw = hw0 + i;
        if (hw < HWSZ) out[(size_t)(b * HWSZ + hw) * CC + c0 + tx] = tile[tx][i];
    }
}

// One block per (roi, ph); thread = channel. acc[7] over pw bins in registers.
template <bool TRANS>
__global__ __launch_bounds__(256) void roipool_k(const float* __restrict__ feat,
                                                 const float* __restrict__ rois,
                                                 const int* __restrict__ ridx,
                                                 float* __restrict__ out) {
    const int r = blockIdx.x;
    const int ph = blockIdx.y;
    const int c = threadIdx.x;

    const float4 rv = reinterpret_cast<const float4*>(rois)[r];
    const int x1 = (int)(rv.x * 0.0625f);
    const int y1 = (int)(rv.y * 0.0625f);
    const int x2 = (int)(rv.z * 0.0625f);
    const int y2 = (int)(rv.w * 0.0625f);
    const int b = ridx[r];
    const int Lh = x2 - x1;
    const int Lw = y2 - y1;

    int hs = x1 + (ph * Lh) / OUTP;
    int he = x1 + ((ph + 1) * Lh + OUTP - 1) / OUTP;
    hs = hs < 0 ? 0 : hs;
    he = he > HH ? HH : he;

    int wss[OUTP], wee[OUTP];
#pragma unroll
    for (int p = 0; p < OUTP; ++p) {
        int w0 = y1 + (p * Lw) / OUTP;
        int w1 = y1 + ((p + 1) * Lw + OUTP - 1) / OUTP;
        wss[p] = w0 < 0 ? 0 : w0;
        wee[p] = w1 > WW ? WW : w1;
    }

    float acc[OUTP];
#pragma unroll
    for (int p = 0; p < OUTP; ++p) acc[p] = NEGV;

    for (int h = hs; h < he; ++h) {
#pragma unroll
        for (int p = 0; p < OUTP; ++p) {
            float m = acc[p];
            for (int w = wss[p]; w < wee[p]; ++w) {
                float v;
                if (TRANS)
                    v = feat[((size_t)(b * HH + h) * WW + w) * CC + c];
                else
                    v = feat[((size_t)(b * CC + c) * HH + h) * WW + w];
                m = fmaxf(m, v);
            }
            acc[p] = m;
        }
    }

    float* op = out + ((size_t)r * CC + c) * (OUTP * OUTP) + (size_t)ph * OUTP;
#pragma unroll
    for (int p = 0; p < OUTP; ++p) op[p] = acc[p];
}

extern "C" void kernel_launch(void* const* d_in, const int* in_sizes, int n_in,
                              void* d_out, int out_size, void* d_ws, size_t ws_size,
                              hipStream_t stream) {
    const float* features = (const float*)d_in[0];
    const float* rois = (const float*)d_in[1];
    const int* ridx = (const int*)d_in[2];
    float* out = (float*)d_out;
    const int R = in_sizes[1] / 4;

    const size_t tbytes = (size_t)BB * HWSZ * CC * sizeof(float);
    if (ws_size >= tbytes) {
        float* featT = (float*)d_ws;
        dim3 tg((HWSZ + 31) / 32, CC / 32, BB);
        transpose_k<<<tg, dim3(32, 8), 0, stream>>>(features, featT);
        roipool_k<true><<<dim3(R, OUTP), 256, 0, stream>>>(featT, rois, ridx, out);
    } else {
        roipool_k<false><<<dim3(R, OUTP), 256, 0, stream>>>(features, rois, ridx, out);
    }
}

// Round 2
// 24.181 us; speedup vs baseline: 1.5273x; 1.5273x over previous
//
#include <hip/hip_runtime.h>
#include <cstddef>
#include <cstdint>

// RoIPool: features (B=2, C=256, H=50, W=50) f32, rois (R,4) f32, roi_indices (R,) int
// out (R, C, 7, 7) f32.
// Reference quirk preserved: h-bins from x coords (ri[:,0], ri[:,2]), w-bins from y.

namespace {
constexpr int OUTP = 7;
constexpr int BB = 2;
constexpr int CC = 256;
constexpr int HH = 50;
constexpr int WW = 50;
constexpr int HWSZ = HH * WW;
constexpr float NEGV = -3e38f;
}  // namespace

// (B, C, H*W) -> (B, H*W, C) tiled transpose via LDS.
__global__ __launch_bounds__(256) void transpose_k(const float* __restrict__ in,
                                                   float* __restrict__ out) {
    __shared__ float tile[32][33];
    const int b = blockIdx.z;
    const int hw0 = blockIdx.x * 32;
    const int c0 = blockIdx.y * 32;
    const int tx = threadIdx.x;
#pragma unroll
    for (int i = threadIdx.y; i < 32; i += 8) {
        const int hw = hw0 + tx;
        float v = 0.0f;
        if (hw < HWSZ) v = in[(size_t)(b * CC + c0 + i) * HWSZ + hw];
        tile[i][tx] = v;
    }
    __syncthreads();
#pragma unroll
    for (int i = threadIdx.y; i < 32; i += 8) {
        const int hw = hw0 + i;
        if (hw < HWSZ) out[(size_t)(b * HWSZ + hw) * CC + c0 + tx] = tile[tx][i];
    }
}

// Fast pool: block = (roi, ph), thread = channel. Bin windows are <=4x4 for the
// given ROI ranges (L = x2-x1 <= 19 -> per-bin span <= 4), so fully unroll with
// scalar row-skip branches + predicated col loads: 28 independent loads in
// flight per row-block instead of 1 (the round-1 latency serialization).
__global__ __launch_bounds__(256) void roipool_fast(const float* __restrict__ feat,
                                                    const float* __restrict__ rois,
                                                    const int* __restrict__ ridx,
                                                    float* __restrict__ out) {
    const int r = blockIdx.x;
    const int ph = blockIdx.y;
    const int c = threadIdx.x;

    const float4 rv = reinterpret_cast<const float4*>(rois)[r];
    int x1 = (int)(rv.x * 0.0625f);
    int y1 = (int)(rv.y * 0.0625f);
    int x2 = (int)(rv.z * 0.0625f);
    int y2 = (int)(rv.w * 0.0625f);
    int b = ridx[r];
    // Force ROI geometry into SGPRs: row/col skip branches become scalar.
    x1 = __builtin_amdgcn_readfirstlane(x1);
    y1 = __builtin_amdgcn_readfirstlane(y1);
    x2 = __builtin_amdgcn_readfirstlane(x2);
    y2 = __builtin_amdgcn_readfirstlane(y2);
    b = __builtin_amdgcn_readfirstlane(b);

    const int Lh = x2 - x1;
    const int Lw = y2 - y1;

    int hs = x1 + (ph * Lh) / OUTP;
    int he = x1 + ((ph + 1) * Lh + OUTP - 1) / OUTP;
    hs = hs < 0 ? 0 : hs;
    he = he > HH ? HH : he;
    const int nh = he - hs;

    int ws_[OUTP], nw_[OUTP];
    int mx = nh;
#pragma unroll
    for (int p = 0; p < OUTP; ++p) {
        int a = y1 + (p * Lw) / OUTP;
        int e = y1 + ((p + 1) * Lw + OUTP - 1) / OUTP;
        a = a < 0 ? 0 : a;
        e = e > WW ? WW : e;
        ws_[p] = a;
        nw_[p] = e - a;
        mx = mx > (e - a) ? mx : (e - a);
    }

    float acc[OUTP];
#pragma unroll
    for (int p = 0; p < OUTP; ++p) acc[p] = NEGV;

    const float* base = feat + ((size_t)(b * HH + hs) * WW) * CC + c;

    if (mx <= 4) {
        // Fast path (always taken for the given ROI ranges).
#pragma unroll
        for (int hh = 0; hh < 4; ++hh) {
            if (hh < nh) {  // scalar branch: skipped rows fetch nothing
                const float* rp = base + (size_t)hh * (WW * CC);
#pragma unroll
                for (int p = 0; p < OUTP; ++p) {
#pragma unroll
                    for (int ww = 0; ww < 4; ++ww) {
                        int col = ws_[p] + ww;
                        col = col > (WW - 1) ? (WW - 1) : col;  // stay in-bounds
                        const float v = rp[(size_t)col * CC];
                        const float vv = (ww < nw_[p]) ? v : NEGV;
                        acc[p] = fmaxf(acc[p], vv);
                    }
                }
            }
        }
    } else {
        // Generic fallback (never taken for this input distribution).
        for (int hh = 0; hh < nh; ++hh) {
            const float* rp = base + (size_t)hh * (WW * CC);
#pragma unroll
            for (int p = 0; p < OUTP; ++p) {
                for (int ww = 0; ww < nw_[p]; ++ww) {
                    acc[p] = fmaxf(acc[p], rp[(size_t)(ws_[p] + ww) * CC]);
                }
            }
        }
    }

    float* op = out + ((size_t)r * CC + c) * (OUTP * OUTP) + (size_t)ph * OUTP;
#pragma unroll
    for (int p = 0; p < OUTP; ++p) op[p] = acc[p];
}

// Generic no-transpose fallback (only if ws_size is too small for featT).
__global__ __launch_bounds__(256) void roipool_generic(const float* __restrict__ feat,
                                                       const float* __restrict__ rois,
                                                       const int* __restrict__ ridx,
                                                       float* __restrict__ out) {
    const int r = blockIdx.x;
    const int ph = blockIdx.y;
    const int c = threadIdx.x;

    const float4 rv = reinterpret_cast<const float4*>(rois)[r];
    const int x1 = (int)(rv.x * 0.0625f);
    const int y1 = (int)(rv.y * 0.0625f);
    const int x2 = (int)(rv.z * 0.0625f);
    const int y2 = (int)(rv.w * 0.0625f);
    const int b = ridx[r];
    const int Lh = x2 - x1;
    const int Lw = y2 - y1;

    int hs = x1 + (ph * Lh) / OUTP;
    int he = x1 + ((ph + 1) * Lh + OUTP - 1) / OUTP;
    hs = hs < 0 ? 0 : hs;
    he = he > HH ? HH : he;

    float acc[OUTP];
#pragma unroll
    for (int p = 0; p < OUTP; ++p) acc[p] = NEGV;

    for (int h = hs; h < he; ++h) {
#pragma unroll
        for (int p = 0; p < OUTP; ++p) {
            int w0 = y1 + (p * Lw) / OUTP;
            int w1 = y1 + ((p + 1) * Lw + OUTP - 1) / OUTP;
            w0 = w0 < 0 ? 0 : w0;
            w1 = w1 > WW ? WW : w1;
            float m = acc[p];
            for (int w = w0; w < w1; ++w) {
                m = fmaxf(m, feat[((size_t)(b * CC + c) * HH + h) * WW + w]);
            }
            acc[p] = m;
        }
    }

    float* op = out + ((size_t)r * CC + c) * (OUTP * OUTP) + (size_t)ph * OUTP;
#pragma unroll
    for (int p = 0; p < OUTP; ++p) op[p] = acc[p];
}

extern "C" void kernel_launch(void* const* d_in, const int* in_sizes, int n_in,
                              void* d_out, int out_size, void* d_ws, size_t ws_size,
                              hipStream_t stream) {
    const float* features = (const float*)d_in[0];
    const float* rois = (const float*)d_in[1];
    const int* ridx = (const int*)d_in[2];
    float* out = (float*)d_out;
    const int R = in_sizes[1] / 4;

    const size_t tbytes = (size_t)BB * HWSZ * CC * sizeof(float);
    if (ws_size >= tbytes) {
        float* featT = (float*)d_ws;
        dim3 tg((HWSZ + 31) / 32, CC / 32, BB);
        transpose_k<<<tg, dim3(32, 8), 0, stream>>>(features, featT);
        roipool_fast<<<dim3(R, OUTP), 256, 0, stream>>>(featT, rois, ridx, out);
    } else {
        roipool_generic<<<dim3(R, OUTP), 256, 0, stream>>>(features, rois, ridx, out);
    }
}

// Round 3
// 21.124 us; speedup vs baseline: 1.7483x; 1.1447x over previous
//
#include <hip/hip_runtime.h>
#include <cstddef>
#include <cstdint>

// RoIPool: features (B=2, C=256, H=50, W=50) f32, rois (R,4) f32, roi_indices (R,) int
// out (R, C, 7, 7) f32.
// Reference quirk preserved: h-bins from x coords (ri[:,0], ri[:,2]), w-bins from y.
//
// Structure: transpose to slice-major (CSPLIT, B, H, W, C/CSPLIT) so each XCD's
// blocks touch only a 1.28 MB channel slice (fits 4 MB per-XCD L2), then one
// 448-thread block per (slice, roi) computes all 7x7 bins and writes its
// contiguous 12.5 KB output chunk via LDS-staged coalesced nontemporal stores.

namespace {
constexpr int OUTP = 7;
constexpr int BB = 2;
constexpr int CC = 256;
constexpr int HH = 50;
constexpr int WW = 50;
constexpr int HWSZ = HH * WW;
constexpr int CSPLIT = 4;
constexpr int CPS = CC / CSPLIT;  // 64 channels per slice
constexpr float NEGV = -3e38f;
}  // namespace

// (B, C, H*W) -> (CSPLIT, B, H*W, CPS) tiled transpose via LDS.
__global__ __launch_bounds__(256) void transpose_k(const float* __restrict__ in,
                                                   float* __restrict__ out) {
    __shared__ float tile[32][33];
    const int b = blockIdx.z;
    const int hw0 = blockIdx.x * 32;
    const int c0 = blockIdx.y * 32;
    const int tx = threadIdx.x;
#pragma unroll
    for (int i = threadIdx.y; i < 32; i += 8) {
        const int hw = hw0 + tx;
        float v = 0.0f;
        if (hw < HWSZ) v = in[(size_t)(b * CC + c0 + i) * HWSZ + hw];
        tile[i][tx] = v;
    }
    __syncthreads();
    const int ch = c0 + tx;          // channel this thread writes
    const int s = ch >> 6;           // slice
    const int cin = ch & 63;         // channel within slice (contiguous in tx)
#pragma unroll
    for (int i = threadIdx.y; i < 32; i += 8) {
        const int hw = hw0 + i;
        if (hw < HWSZ)
            out[((size_t)((s * BB + b) * HWSZ) + hw) * CPS + cin] = tile[tx][i];
    }
}

// Pool: grid (CSPLIT, R), block 448 = 7 waves; wave = ph, lane = channel-in-slice.
__global__ __launch_bounds__(448) void roipool3(const float* __restrict__ feat,
                                                const float* __restrict__ rois,
                                                const int* __restrict__ ridx,
                                                float* __restrict__ out) {
    const int s = blockIdx.x;
    const int r = blockIdx.y;
    const int tid = threadIdx.x;
    const int c = tid & 63;
    const int ph = __builtin_amdgcn_readfirstlane(tid >> 6);  // wave-uniform

    const float4 rv = reinterpret_cast<const float4*>(rois)[r];
    int x1 = (int)(rv.x * 0.0625f);
    int y1 = (int)(rv.y * 0.0625f);
    int x2 = (int)(rv.z * 0.0625f);
    int y2 = (int)(rv.w * 0.0625f);
    int b = ridx[r];
    x1 = __builtin_amdgcn_readfirstlane(x1);
    y1 = __builtin_amdgcn_readfirstlane(y1);
    x2 = __builtin_amdgcn_readfirstlane(x2);
    y2 = __builtin_amdgcn_readfirstlane(y2);
    b = __builtin_amdgcn_readfirstlane(b);

    const int Lh = x2 - x1;
    const int Lw = y2 - y1;

    int hs = x1 + (ph * Lh) / OUTP;
    int he = x1 + ((ph + 1) * Lh + OUTP - 1) / OUTP;
    hs = hs < 0 ? 0 : hs;
    he = he > HH ? HH : he;
    const int nh = he - hs;

    int ws_[OUTP], nw_[OUTP];
    int mx = nh;
#pragma unroll
    for (int p = 0; p < OUTP; ++p) {
        int a = y1 + (p * Lw) / OUTP;
        int e = y1 + ((p + 1) * Lw + OUTP - 1) / OUTP;
        a = a < 0 ? 0 : a;
        e = e > WW ? WW : e;
        ws_[p] = a;
        nw_[p] = e - a;
        mx = mx > (e - a) ? mx : (e - a);
    }

    float acc[OUTP];
#pragma unroll
    for (int p = 0; p < OUTP; ++p) acc[p] = NEGV;

    const float* base = feat + ((size_t)((s * BB + b) * HWSZ) + (size_t)hs * WW) * CPS + c;

    if (mx <= 4) {
        // Fast path (always taken: L = x2-x1 in [4,19] -> per-bin span <= 4).
#pragma unroll
        for (int hh = 0; hh < 4; ++hh) {
            if (hh < nh) {  // scalar branch: skipped rows fetch nothing
                const float* rp = base + (size_t)hh * (WW * CPS);
#pragma unroll
                for (int p = 0; p < OUTP; ++p) {
#pragma unroll
                    for (int ww = 0; ww < 4; ++ww) {
                        int col = ws_[p] + ww;
                        col = col > (WW - 1) ? (WW - 1) : col;  // stay in-bounds
                        const float v = rp[(size_t)col * CPS];
                        const float vv = (ww < nw_[p]) ? v : NEGV;
                        acc[p] = fmaxf(acc[p], vv);
                    }
                }
            }
        }
    } else {
        // Generic fallback (never taken for this input distribution).
        for (int hh = 0; hh < nh; ++hh) {
            const float* rp = base + (size_t)hh * (WW * CPS);
#pragma unroll
            for (int p = 0; p < OUTP; ++p) {
                for (int ww = 0; ww < nw_[p]; ++ww) {
                    acc[p] = fmaxf(acc[p], rp[(size_t)(ws_[p] + ww) * CPS]);
                }
            }
        }
    }

    // Stage to LDS: [64 channels][49 bins], stride 49 (odd) -> conflict-free.
    __shared__ float st[CPS * OUTP * OUTP];
#pragma unroll
    for (int p = 0; p < OUTP; ++p) st[c * 49 + ph * OUTP + p] = acc[p];
    __syncthreads();

    // Coalesced nontemporal copy-out: 3136 floats = 448 threads x 7.
    float* ob = out + ((size_t)(r * CC + s * CPS)) * (OUTP * OUTP);
#pragma unroll
    for (int k = 0; k < OUTP; ++k) {
        __builtin_nontemporal_store(st[tid + k * 448], ob + tid + k * 448);
    }
}

// Generic no-transpose fallback (only if ws_size is too small for featT).
__global__ __launch_bounds__(256) void roipool_generic(const float* __restrict__ feat,
                                                       const float* __restrict__ rois,
                                                       const int* __restrict__ ridx,
                                                       float* __restrict__ out) {
    const int r = blockIdx.x;
    const int ph = blockIdx.y;
    const int c = threadIdx.x;

    const float4 rv = reinterpret_cast<const float4*>(rois)[r];
    const int x1 = (int)(rv.x * 0.0625f);
    const int y1 = (int)(rv.y * 0.0625f);
    const int x2 = (int)(rv.z * 0.0625f);
    const int y2 = (int)(rv.w * 0.0625f);
    const int b = ridx[r];
    const int Lh = x2 - x1;
    const int Lw = y2 - y1;

    int hs = x1 + (ph * Lh) / OUTP;
    int he = x1 + ((ph + 1) * Lh + OUTP - 1) / OUTP;
    hs = hs < 0 ? 0 : hs;
    he = he > HH ? HH : he;

    float acc[OUTP];
#pragma unroll
    for (int p = 0; p < OUTP; ++p) acc[p] = NEGV;

    for (int h = hs; h < he; ++h) {
#pragma unroll
        for (int p = 0; p < OUTP; ++p) {
            int w0 = y1 + (p * Lw) / OUTP;
            int w1 = y1 + ((p + 1) * Lw + OUTP - 1) / OUTP;
            w0 = w0 < 0 ? 0 : w0;
            w1 = w1 > WW ? WW : w1;
            float m = acc[p];
            for (int w = w0; w < w1; ++w) {
                m = fmaxf(m, feat[((size_t)(b * CC + c) * HH + h) * WW + w]);
            }
            acc[p] = m;
        }
    }

    float* op = out + ((size_t)r * CC + c) * (OUTP * OUTP) + (size_t)ph * OUTP;
#pragma unroll
    for (int p = 0; p < OUTP; ++p) op[p] = acc[p];
}

extern "C" void kernel_launch(void* const* d_in, const int* in_sizes, int n_in,
                              void* d_out, int out_size, void* d_ws, size_t ws_size,
                              hipStream_t stream) {
    const float* features = (const float*)d_in[0];
    const float* rois = (const float*)d_in[1];
    const int* ridx = (const int*)d_in[2];
    float* out = (float*)d_out;
    const int R = in_sizes[1] / 4;

    const size_t tbytes = (size_t)BB * HWSZ * CC * sizeof(float);
    if (ws_size >= tbytes && (R % 1) == 0) {
        float* featT = (float*)d_ws;
        dim3 tg((HWSZ + 31) / 32, CC / 32, BB);
        transpose_k<<<tg, dim3(32, 8), 0, stream>>>(features, featT);
        roipool3<<<dim3(CSPLIT, R), 448, 0, stream>>>(featT, rois, ridx, out);
    } else {
        roipool_generic<<<dim3(R, OUTP), 256, 0, stream>>>(features, rois, ridx, out);
    }
}